// Round 1
// baseline (502.108 us; speedup 1.0000x reference)
//
#include <hip/hip_runtime.h>

typedef __attribute__((ext_vector_type(8))) short bf16x8;
typedef __attribute__((ext_vector_type(4))) float f32x4;

__device__ __forceinline__ ushort f2bf(float x) {
  union { float f; unsigned u; } c; c.f = x;
  unsigned u = c.u;
  u += 0x7fffu + ((u >> 16) & 1u);
  return (ushort)(u >> 16);
}

// ---------------------------------------------------------------------------
// Transpose A,B [4][4096][128] f32 -> At,Bt [4][128][4096] bf16 (V operands)
// ---------------------------------------------------------------------------
__global__ __launch_bounds__(256) void prep_transpose(
    const float* __restrict__ A, const float* __restrict__ Bm,
    ushort* __restrict__ At, ushort* __restrict__ Bt)
{
  int tensor = blockIdx.z & 1, b = blockIdx.z >> 1;
  const float* in = tensor ? Bm : A;
  ushort* out = tensor ? Bt : At;
  int m0 = blockIdx.x * 64, d0 = blockIdx.y * 64;
  __shared__ ushort tile[64][72];
  int tid = threadIdx.x;
#pragma unroll
  for (int it = 0; it < 4; ++it) {
    int lin = it * 256 + tid;
    int r = lin >> 4, c4 = (lin & 15) * 4;
    const float* p = in + ((size_t)b * 4096 + m0 + r) * 128 + d0 + c4;
    float4 v = *(const float4*)p;
    tile[r][c4 + 0] = f2bf(v.x); tile[r][c4 + 1] = f2bf(v.y);
    tile[r][c4 + 2] = f2bf(v.z); tile[r][c4 + 3] = f2bf(v.w);
  }
  __syncthreads();
#pragma unroll
  for (int it = 0; it < 2; ++it) {
    int lin = it * 256 + tid;
    int dr = lin >> 3, cm = (lin & 7) * 8;
    bf16x8 v;
#pragma unroll
    for (int j = 0; j < 8; ++j) v[j] = (short)tile[cm + j][dr];
    *(bf16x8*)(out + ((size_t)b * 128 + d0 + dr) * 4096 + m0 + cm) = v;
  }
}

// ---------------------------------------------------------------------------
// C_bf16 = relu(X @ W + bias), N = 256 fixed. X: [16384][KDIM] (f32 or bf16)
// block = 256 thr (4 waves), 64 rows/block, full N. 16x16x32 bf16 MFMA.
// ---------------------------------------------------------------------------
template<int KDIM, bool F32IN>
__global__ __launch_bounds__(256) void mlp_gemm(
    const void* __restrict__ X0, const void* __restrict__ X1,
    const float* __restrict__ W, const float* __restrict__ bias,
    ushort* __restrict__ out0, ushort* __restrict__ out1)
{
  const void* X = blockIdx.y ? X1 : X0;
  ushort* out = blockIdx.y ? out1 : out0;
  int lane = threadIdx.x & 63, w = threadIdx.x >> 6;
  int rowbase = blockIdx.x * 64 + w * 16;
  constexpr int NK = KDIM / 32;
  bf16x8 xf[NK];
  {
    int r = rowbase + (lane & 15);
    int koff = (lane >> 4) * 8;
    if (F32IN) {
      const float* Xp = (const float*)X + (size_t)r * KDIM + koff;
#pragma unroll
      for (int kc = 0; kc < NK; ++kc) {
        float4 a = *(const float4*)(Xp + kc * 32);
        float4 c = *(const float4*)(Xp + kc * 32 + 4);
        bf16x8 v;
        v[0] = (short)f2bf(a.x); v[1] = (short)f2bf(a.y);
        v[2] = (short)f2bf(a.z); v[3] = (short)f2bf(a.w);
        v[4] = (short)f2bf(c.x); v[5] = (short)f2bf(c.y);
        v[6] = (short)f2bf(c.z); v[7] = (short)f2bf(c.w);
        xf[kc] = v;
      }
    } else {
      const ushort* Xp = (const ushort*)X + (size_t)r * KDIM + koff;
#pragma unroll
      for (int kc = 0; kc < NK; ++kc) xf[kc] = *(const bf16x8*)(Xp + kc * 32);
    }
  }
  __shared__ ushort Wt[256][72];   // W^T chunk: [n][k(64)] bf16, padded
  f32x4 acc[16];
#pragma unroll
  for (int i = 0; i < 16; ++i) acc[i] = (f32x4){0.f, 0.f, 0.f, 0.f};

  for (int kb = 0; kb < KDIM / 64; ++kb) {
    if (kb) __syncthreads();
#pragma unroll
    for (int it = 0; it < 16; ++it) {
      int lin = it * 256 + threadIdx.x;     // 4096 float4 = 64x256 f32
      int kr = lin >> 6, nc = (lin & 63) * 4;
      float4 v = *(const float4*)(W + ((size_t)(kb * 64 + kr)) * 256 + nc);
      Wt[nc + 0][kr] = f2bf(v.x); Wt[nc + 1][kr] = f2bf(v.y);
      Wt[nc + 2][kr] = f2bf(v.z); Wt[nc + 3][kr] = f2bf(v.w);
    }
    __syncthreads();
#pragma unroll
    for (int kc2 = 0; kc2 < 2; ++kc2) {
      int kcg = kb * 2 + kc2;
#pragma unroll
      for (int nf = 0; nf < 16; ++nf) {
        bf16x8 bfv = *(const bf16x8*)&Wt[nf * 16 + (lane & 15)][kc2 * 32 + (lane >> 4) * 8];
        acc[nf] = __builtin_amdgcn_mfma_f32_16x16x32_bf16(xf[kcg], bfv, acc[nf], 0, 0, 0);
      }
    }
  }
#pragma unroll
  for (int nf = 0; nf < 16; ++nf) {
    int col = nf * 16 + (lane & 15);
    float bv = bias[col];
#pragma unroll
    for (int i = 0; i < 4; ++i) {
      float v = acc[nf][i] + bv;
      v = fmaxf(v, 0.f);
      out[(size_t)(rowbase + (lane >> 4) * 4 + i) * 256 + col] = f2bf(v);
    }
  }
}

// ---------------------------------------------------------------------------
// Flash pass: O = softmax_rows(Q @ K^T) @ V.  Q,K: [4][4096][256] bf16,
// V given transposed [4][128][4096] bf16. grid.z selects (beta, alpha) pass.
// block = 256 thr (4 waves); 64 q-rows/block (16/wave); key tiles of 64.
// ---------------------------------------------------------------------------
__global__ __launch_bounds__(256) void flash_attend(
    const ushort* __restrict__ fA, const ushort* __restrict__ fB,
    const ushort* __restrict__ At, const ushort* __restrict__ Bt,
    float* __restrict__ out)
{
  int pass = blockIdx.z;
  int b = blockIdx.y;
  int qbase = blockIdx.x * 64;
  const ushort* fQ = pass ? fB : fA;
  const ushort* fK = pass ? fA : fB;
  const ushort* Vg = pass ? At : Bt;
  float* O = out + (size_t)pass * 2097152;

  int lane = threadIdx.x & 63, w = threadIdx.x >> 6;
  __shared__ ushort Klds[64][264];   // [key][h]   33 KB
  __shared__ ushort Vt[128][72];     // [d][key]   18 KB
  __shared__ ushort Plds[4][16][72]; // per-wave P  9 KB

  bf16x8 q[8];
  {
    const ushort* qp = fQ + ((size_t)b * 4096 + qbase + w * 16 + (lane & 15)) * 256 + (lane >> 4) * 8;
#pragma unroll
    for (int kc = 0; kc < 8; ++kc) q[kc] = *(const bf16x8*)(qp + kc * 32);
  }
  f32x4 acc_o[8];
#pragma unroll
  for (int i = 0; i < 8; ++i) acc_o[i] = (f32x4){0.f, 0.f, 0.f, 0.f};
  float m_run[4] = {-INFINITY, -INFINITY, -INFINITY, -INFINITY};
  float l_run[4] = {0.f, 0.f, 0.f, 0.f};

  for (int t = 0; t < 64; ++t) {
    // stage K tile [64][256]
#pragma unroll
    for (int it = 0; it < 8; ++it) {
      int lin = it * 256 + threadIdx.x;
      int r = lin >> 5, c8 = (lin & 31) * 8;
      *(bf16x8*)&Klds[r][c8] =
          *(const bf16x8*)(fK + ((size_t)b * 4096 + t * 64 + r) * 256 + c8);
    }
    // stage V tile [128][64] (already transposed in global)
#pragma unroll
    for (int it = 0; it < 4; ++it) {
      int lin = it * 256 + threadIdx.x;
      int d = lin >> 3, c8 = (lin & 7) * 8;
      *(bf16x8*)&Vt[d][c8] =
          *(const bf16x8*)(Vg + ((size_t)b * 128 + d) * 4096 + t * 64 + c8);
    }
    __syncthreads();

    // S = Q K^T for this wave's 16 rows x 64 keys
    f32x4 accs[4];
#pragma unroll
    for (int nf = 0; nf < 4; ++nf) accs[nf] = (f32x4){0.f, 0.f, 0.f, 0.f};
#pragma unroll
    for (int kc = 0; kc < 8; ++kc) {
#pragma unroll
      for (int nf = 0; nf < 4; ++nf) {
        bf16x8 kf = *(const bf16x8*)&Klds[nf * 16 + (lane & 15)][kc * 32 + (lane >> 4) * 8];
        accs[nf] = __builtin_amdgcn_mfma_f32_16x16x32_bf16(q[kc], kf, accs[nf], 0, 0, 0);
      }
    }

    // online softmax, 4 rows per lane (row = (lane>>4)*4 + i)
#pragma unroll
    for (int i = 0; i < 4; ++i) {
      float mx = fmaxf(fmaxf(accs[0][i], accs[1][i]), fmaxf(accs[2][i], accs[3][i]));
#pragma unroll
      for (int d = 1; d < 16; d <<= 1) mx = fmaxf(mx, __shfl_xor(mx, d));
      float mnew = fmaxf(m_run[i], mx);
      float sc = __expf(m_run[i] - mnew);
      float psum = 0.f;
      int prow = (lane >> 4) * 4 + i;
#pragma unroll
      for (int nf = 0; nf < 4; ++nf) {
        float p = __expf(accs[nf][i] - mnew);
        psum += p;
        Plds[w][prow][nf * 16 + (lane & 15)] = f2bf(p);
      }
#pragma unroll
      for (int d = 1; d < 16; d <<= 1) psum += __shfl_xor(psum, d);
      l_run[i] = l_run[i] * sc + psum;
      m_run[i] = mnew;
#pragma unroll
      for (int vf = 0; vf < 8; ++vf) acc_o[vf][i] *= sc;
    }

    // O += P @ V  (P from per-wave LDS; same-wave RAW ordered by compiler)
#pragma unroll
    for (int kc2 = 0; kc2 < 2; ++kc2) {
      bf16x8 pa = *(const bf16x8*)&Plds[w][lane & 15][kc2 * 32 + (lane >> 4) * 8];
#pragma unroll
      for (int vf = 0; vf < 8; ++vf) {
        bf16x8 vv = *(const bf16x8*)&Vt[vf * 16 + (lane & 15)][kc2 * 32 + (lane >> 4) * 8];
        acc_o[vf] = __builtin_amdgcn_mfma_f32_16x16x32_bf16(pa, vv, acc_o[vf], 0, 0, 0);
      }
    }
    __syncthreads();
  }

#pragma unroll
  for (int i = 0; i < 4; ++i) {
    float inv = 1.f / l_run[i];
    int row = qbase + w * 16 + (lane >> 4) * 4 + i;
    float* op = O + ((size_t)b * 4096 + row) * 128 + (lane & 15);
#pragma unroll
    for (int vf = 0; vf < 8; ++vf) op[vf * 16] = acc_o[vf][i] * inv;
  }
}

// ---------------------------------------------------------------------------
extern "C" void kernel_launch(void* const* d_in, const int* in_sizes, int n_in,
                              void* d_out, int out_size, void* d_ws, size_t ws_size,
                              hipStream_t stream) {
  const float* A  = (const float*)d_in[0];
  const float* Bm = (const float*)d_in[1];
  const float* W1 = (const float*)d_in[2];
  const float* b1 = (const float*)d_in[3];
  const float* W2 = (const float*)d_in[4];
  const float* b2 = (const float*)d_in[5];
  float* out = (float*)d_out;

  // ws layout (bf16 elements): hA,hB,fA,fB [16384][256]; At,Bt [4][128][4096]
  ushort* ws = (ushort*)d_ws;
  ushort* hA = ws;
  ushort* hB = hA + 4194304;
  ushort* fA = hB + 4194304;
  ushort* fB = fA + 4194304;
  ushort* At = fB + 4194304;
  ushort* Bt = At + 2097152;   // total 40 MB

  prep_transpose<<<dim3(64, 2, 8), 256, 0, stream>>>(A, Bm, At, Bt);
  mlp_gemm<128, true ><<<dim3(256, 2), 256, 0, stream>>>(A, Bm, W1, b1, hA, hB);
  mlp_gemm<256, false><<<dim3(256, 2), 256, 0, stream>>>(hA, hB, W2, b2, fA, fB);
  flash_attend<<<dim3(64, 4, 2), 256, 0, stream>>>(fA, fB, At, Bt, out);
}

// Round 2
// 307.458 us; speedup vs baseline: 1.6331x; 1.6331x over previous
//
#include <hip/hip_runtime.h>

typedef __attribute__((ext_vector_type(8))) short bf16x8;
typedef __attribute__((ext_vector_type(4))) float f32x4;
typedef __attribute__((ext_vector_type(16))) float f32x16;

__device__ __forceinline__ ushort f2bf(float x) {
  union { float f; unsigned u; } c; c.f = x;
  unsigned u = c.u;
  u += 0x7fffu + ((u >> 16) & 1u);
  return (ushort)(u >> 16);
}

__device__ __forceinline__ unsigned cvt_pk_bf16(float lo, float hi) {
  unsigned r;
  asm("v_cvt_pk_bf16_f32 %0, %1, %2" : "=v"(r) : "v"(lo), "v"(hi));
  return r;
}

__device__ __forceinline__ void gl_lds16(const void* g, void* s) {
  __builtin_amdgcn_global_load_lds(
      (const __attribute__((address_space(1))) unsigned*)g,
      (__attribute__((address_space(3))) unsigned*)s, 16, 0, 0);
}

// ---------------------------------------------------------------------------
// Transpose A,B [4][4096][128] f32 -> At,Bt [4][128][4096] bf16 (V^T operands)
// ---------------------------------------------------------------------------
__global__ __launch_bounds__(256) void prep_transpose(
    const float* __restrict__ A, const float* __restrict__ Bm,
    ushort* __restrict__ At, ushort* __restrict__ Bt)
{
  int tensor = blockIdx.z & 1, b = blockIdx.z >> 1;
  const float* in = tensor ? Bm : A;
  ushort* out = tensor ? Bt : At;
  int m0 = blockIdx.x * 64, d0 = blockIdx.y * 64;
  __shared__ ushort tile[64][72];
  int tid = threadIdx.x;
#pragma unroll
  for (int it = 0; it < 4; ++it) {
    int lin = it * 256 + tid;
    int r = lin >> 4, c4 = (lin & 15) * 4;
    const float* p = in + ((size_t)b * 4096 + m0 + r) * 128 + d0 + c4;
    float4 v = *(const float4*)p;
    tile[r][c4 + 0] = f2bf(v.x); tile[r][c4 + 1] = f2bf(v.y);
    tile[r][c4 + 2] = f2bf(v.z); tile[r][c4 + 3] = f2bf(v.w);
  }
  __syncthreads();
#pragma unroll
  for (int it = 0; it < 2; ++it) {
    int lin = it * 256 + tid;
    int dr = lin >> 3, cm = (lin & 7) * 8;
    bf16x8 v;
#pragma unroll
    for (int j = 0; j < 8; ++j) v[j] = (short)tile[cm + j][dr];
    *(bf16x8*)(out + ((size_t)b * 128 + d0 + dr) * 4096 + m0 + cm) = v;
  }
}

// ---------------------------------------------------------------------------
// W1[128][256] -> Wt1[256][128] bf16 ; W2[256][256] -> Wt2[256][256] bf16
// ---------------------------------------------------------------------------
__global__ __launch_bounds__(256) void prep_w(
    const float* __restrict__ W1, const float* __restrict__ W2,
    ushort* __restrict__ Wt1, ushort* __restrict__ Wt2)
{
  int idx = blockIdx.x * 256 + threadIdx.x;   // 0..65535
  if (idx < 32768) {
    int k = idx >> 8, n = idx & 255;
    Wt1[n * 128 + k] = f2bf(W1[idx]);
  }
  {
    int k = idx >> 8, n = idx & 255;
    Wt2[n * 256 + k] = f2bf(W2[idx]);
  }
}

// ---------------------------------------------------------------------------
// out = relu(X @ W + bias) bf16, N=256. Wt bf16 [256][KD] from global (L2).
// 4 waves x 16 rows = 64 rows/block. No LDS, no barriers.
// ---------------------------------------------------------------------------
template<int KD, bool F32IN>
__global__ __launch_bounds__(256) void mlp2(
    const void* __restrict__ X0, const void* __restrict__ X1,
    const ushort* __restrict__ Wt, const float* __restrict__ bias,
    ushort* __restrict__ out0, ushort* __restrict__ out1)
{
  const void* X = blockIdx.y ? X1 : X0;
  ushort* out = blockIdx.y ? out1 : out0;
  int l = threadIdx.x & 63, w = threadIdx.x >> 6;
  int rowbase = blockIdx.x * 64 + w * 16;
  constexpr int NK = KD / 32;
  bf16x8 xf[NK];
  {
    int r = rowbase + (l & 15);
    int koff = (l >> 4) * 8;
    if (F32IN) {
      const float* Xp = (const float*)X + (size_t)r * KD + koff;
#pragma unroll
      for (int kc = 0; kc < NK; ++kc) {
        float4 a = *(const float4*)(Xp + kc * 32);
        float4 c = *(const float4*)(Xp + kc * 32 + 4);
        bf16x8 v;
        v[0] = (short)f2bf(a.x); v[1] = (short)f2bf(a.y);
        v[2] = (short)f2bf(a.z); v[3] = (short)f2bf(a.w);
        v[4] = (short)f2bf(c.x); v[5] = (short)f2bf(c.y);
        v[6] = (short)f2bf(c.z); v[7] = (short)f2bf(c.w);
        xf[kc] = v;
      }
    } else {
      const ushort* Xp = (const ushort*)X + (size_t)r * KD + koff;
#pragma unroll
      for (int kc = 0; kc < NK; ++kc) xf[kc] = *(const bf16x8*)(Xp + kc * 32);
    }
  }
  f32x4 acc[16];
#pragma unroll
  for (int i = 0; i < 16; ++i) acc[i] = (f32x4){0.f, 0.f, 0.f, 0.f};
#pragma unroll
  for (int kc = 0; kc < NK; ++kc) {
#pragma unroll
    for (int nf = 0; nf < 16; ++nf) {
      bf16x8 bfv = *(const bf16x8*)&Wt[(size_t)(nf * 16 + (l & 15)) * KD + kc * 32 + (l >> 4) * 8];
      acc[nf] = __builtin_amdgcn_mfma_f32_16x16x32_bf16(xf[kc], bfv, acc[nf], 0, 0, 0);
    }
  }
#pragma unroll
  for (int nf = 0; nf < 16; ++nf) {
    int col = nf * 16 + (l & 15);
    float bv = bias[col];
#pragma unroll
    for (int i = 0; i < 4; ++i) {
      float v = acc[nf][i] + bv;
      v = fmaxf(v, 0.f);
      out[(size_t)(rowbase + (l >> 4) * 4 + i) * 256 + col] = f2bf(v);
    }
  }
}

// ---------------------------------------------------------------------------
// Flash pass, 32x32x16 MFMA, swapped QK^T, in-register P, defer-max.
// Block: 4 waves x 32 q-rows = 128 rows. Grid (8, 32): x = pass*4+b (XCD-major).
// K tile [64][256] bf16 in LDS (dbuf, global_load_lds, XOR-swizzled 16B
// granules: LDS[r][g] = G[r][g ^ (r&7)]). V^T read from global (L2-resident).
// ---------------------------------------------------------------------------
__global__ __launch_bounds__(256, 1) void flash2(
    const ushort* __restrict__ fA, const ushort* __restrict__ fB,
    const ushort* __restrict__ At, const ushort* __restrict__ Bt,
    float* __restrict__ out)
{
  int bp = blockIdx.x;
  int pass = bp >> 2, b = bp & 3;
  int qbase = blockIdx.y * 128;
  const ushort* fQ = pass ? fB : fA;
  const ushort* fK = pass ? fA : fB;
  const ushort* Vg = pass ? At : Bt;
  float* O = out + (size_t)pass * (4u * 4096 * 128) + (size_t)b * 4096 * 128;

  __shared__ ushort Kl[2][64 * 256];   // 64 KB

  int tid = threadIdx.x;
  int l = tid & 63, w = tid >> 6;
  int l31 = l & 31, g5 = l >> 5;

  const size_t fkbase = (size_t)b * 4096 * 256;
  const size_t vgbase = (size_t)b * 128 * 4096;

  auto stage_k = [&](int t_, int buf_) {
    const ushort* kp = fK + fkbase + (size_t)t_ * 16384;
    ushort* lb = &Kl[buf_][0] + w * 4096;
#pragma unroll
    for (int s = 0; s < 8; ++s) {
      int row = w * 16 + s * 2 + g5;
      int gs = l31 ^ (row & 7);
      gl_lds16(kp + (size_t)row * 256 + gs * 8, lb + s * 512);
    }
  };

  // Q regs: B-frag (col = l31 -> qrow, k = kc*16 + g5*8 + j)
  bf16x8 q[16];
  {
    const ushort* qp = fQ + fkbase + (size_t)(qbase + w * 32 + l31) * 256 + g5 * 8;
#pragma unroll
    for (int kc = 0; kc < 16; ++kc) q[kc] = *(const bf16x8*)(qp + kc * 16);
  }

  f32x16 acc_o0 = {}, acc_o1 = {}, acc_o2 = {}, acc_o3 = {};
  float m_run = -INFINITY, l_run = 0.f;

  stage_k(0, 0);

  for (int t = 0; t < 64; ++t) {
    int cur = t & 1;
    __syncthreads();               // staged K[t] drained; prev reads done
    if (t < 63) stage_k(t + 1, cur ^ 1);

    // V^T loads for this tile, issued early (global/L2).
    // B-frag for PV: col = l31 -> d-local, k = key = kblk*16 + g5*8 + j
    bf16x8 vv[4][4];
#pragma unroll
    for (int dblk = 0; dblk < 4; ++dblk) {
      const ushort* vp = Vg + vgbase + (size_t)(dblk * 32 + l31) * 4096 + t * 64 + g5 * 8;
#pragma unroll
      for (int kblk = 0; kblk < 4; ++kblk)
        vv[kblk][dblk] = *(const bf16x8*)(vp + kblk * 16);
    }

    // QK^T swapped: S^T[key][qrow] = mfma(A=K, B=Q). 4 indep chains.
    const ushort* kbuf = &Kl[cur][0];
    f32x16 s00 = {}, s01 = {}, s10 = {}, s11 = {};
#pragma unroll
    for (int kc = 0; kc < 8; ++kc) {
      int r0 = l31, r1 = 32 + l31;
      int sx = r0 & 7;             // == r1 & 7
      bf16x8 a00 = *(const bf16x8*)&kbuf[r0 * 256 + (((4 * kc + g5) ^ sx) * 8)];
      bf16x8 a10 = *(const bf16x8*)&kbuf[r1 * 256 + (((4 * kc + g5) ^ sx) * 8)];
      bf16x8 a01 = *(const bf16x8*)&kbuf[r0 * 256 + (((4 * kc + 2 + g5) ^ sx) * 8)];
      bf16x8 a11 = *(const bf16x8*)&kbuf[r1 * 256 + (((4 * kc + 2 + g5) ^ sx) * 8)];
      s00 = __builtin_amdgcn_mfma_f32_32x32x16_bf16(a00, q[2 * kc],     s00, 0, 0, 0);
      s10 = __builtin_amdgcn_mfma_f32_32x32x16_bf16(a10, q[2 * kc],     s10, 0, 0, 0);
      s01 = __builtin_amdgcn_mfma_f32_32x32x16_bf16(a01, q[2 * kc + 1], s01, 0, 0, 0);
      s11 = __builtin_amdgcn_mfma_f32_32x32x16_bf16(a11, q[2 * kc + 1], s11, 0, 0, 0);
    }

    // Per lane: qrow = l31; key(kb, r) = 32*kb + (r&3) + 8*(r>>2) + 4*g5
    float sv0[16], sv1[16];
#pragma unroll
    for (int r = 0; r < 16; ++r) { sv0[r] = s00[r] + s01[r]; sv1[r] = s10[r] + s11[r]; }

    float pmax = sv0[0];
#pragma unroll
    for (int r = 0; r < 16; ++r) { pmax = fmaxf(pmax, sv0[r]); pmax = fmaxf(pmax, sv1[r]); }
    pmax = fmaxf(pmax, __shfl_xor(pmax, 32));

    if (!__all(pmax <= m_run + 8.f)) {       // rare (t=0 and overflow risk only)
      float mnew = fmaxf(m_run, pmax);
      float sc = __expf(m_run - mnew);
      l_run *= sc;
#pragma unroll
      for (int r = 0; r < 16; ++r) {
        float scr = __shfl(sc, (r & 3) + 8 * (r >> 2) + 4 * g5);
        acc_o0[r] *= scr; acc_o1[r] *= scr; acc_o2[r] *= scr; acc_o3[r] *= scr;
      }
      m_run = mnew;
    }

    float p0[16], p1[16], psum = 0.f;
#pragma unroll
    for (int r = 0; r < 16; ++r) {
      p0[r] = __expf(sv0[r] - m_run);
      p1[r] = __expf(sv1[r] - m_run);
      psum += p0[r] + p1[r];
    }
    l_run += psum + __shfl_xor(psum, 32);

    // pack P: pk[kb][r2][h] = keys 4*(8kb + 2r2 + g5) + {0..3}
    unsigned pk0[4][2], pk1[4][2];
#pragma unroll
    for (int r2 = 0; r2 < 4; ++r2) {
      pk0[r2][0] = cvt_pk_bf16(p0[4 * r2 + 0], p0[4 * r2 + 1]);
      pk0[r2][1] = cvt_pk_bf16(p0[4 * r2 + 2], p0[4 * r2 + 3]);
      pk1[r2][0] = cvt_pk_bf16(p1[4 * r2 + 0], p1[4 * r2 + 1]);
      pk1[r2][1] = cvt_pk_bf16(p1[4 * r2 + 2], p1[4 * r2 + 3]);
    }

    // exchange halves (lane <-> lane^32) -> PV A-frags; then PV MFMAs.
#pragma unroll
    for (int kblk = 0; kblk < 4; ++kblk) {
      int r2a = 2 * (kblk & 1), r2b = r2a + 1;
      unsigned la0, la1, lb0, lb1;
      if (kblk < 2) { la0 = pk0[r2a][0]; la1 = pk0[r2a][1]; lb0 = pk0[r2b][0]; lb1 = pk0[r2b][1]; }
      else          { la0 = pk1[r2a][0]; la1 = pk1[r2a][1]; lb0 = pk1[r2b][0]; lb1 = pk1[r2b][1]; }
      unsigned s0 = g5 ? la0 : lb0, s1 = g5 ? la1 : lb1;
      unsigned rc0 = (unsigned)__shfl_xor((int)s0, 32);
      unsigned rc1 = (unsigned)__shfl_xor((int)s1, 32);
      union { unsigned u[4]; bf16x8 v; } pf;
      pf.u[0] = g5 ? rc0 : la0;  pf.u[1] = g5 ? rc1 : la1;
      pf.u[2] = g5 ? lb0 : rc0;  pf.u[3] = g5 ? lb1 : rc1;
      acc_o0 = __builtin_amdgcn_mfma_f32_32x32x16_bf16(pf.v, vv[kblk][0], acc_o0, 0, 0, 0);
      acc_o1 = __builtin_amdgcn_mfma_f32_32x32x16_bf16(pf.v, vv[kblk][1], acc_o1, 0, 0, 0);
      acc_o2 = __builtin_amdgcn_mfma_f32_32x32x16_bf16(pf.v, vv[kblk][2], acc_o2, 0, 0, 0);
      acc_o3 = __builtin_amdgcn_mfma_f32_32x32x16_bf16(pf.v, vv[kblk][3], acc_o3, 0, 0, 0);
    }
  }

  // epilogue: O[qrow][d] = acc_o * (1/l); coalesced 128B stores per r.
  float inv = 1.f / l_run;
  int qr = qbase + w * 32;
#pragma unroll
  for (int r = 0; r < 16; ++r) {
    int rowl = (r & 3) + 8 * (r >> 2) + 4 * g5;
    float invr = __shfl(inv, rowl);
    float* op = O + (size_t)(qr + rowl) * 128 + l31;
    op[0]  = acc_o0[r] * invr;
    op[32] = acc_o1[r] * invr;
    op[64] = acc_o2[r] * invr;
    op[96] = acc_o3[r] * invr;
  }
}

// ---------------------------------------------------------------------------
extern "C" void kernel_launch(void* const* d_in, const int* in_sizes, int n_in,
                              void* d_out, int out_size, void* d_ws, size_t ws_size,
                              hipStream_t stream) {
  const float* A  = (const float*)d_in[0];
  const float* Bm = (const float*)d_in[1];
  const float* W1 = (const float*)d_in[2];
  const float* b1 = (const float*)d_in[3];
  const float* W2 = (const float*)d_in[4];
  const float* b2 = (const float*)d_in[5];
  float* out = (float*)d_out;

  // ws (ushort units): hA,hB,fA,fB [16384][256]; At,Bt [4][128][4096]; Wt1,Wt2
  ushort* ws = (ushort*)d_ws;
  ushort* hA  = ws;
  ushort* hB  = hA + 4194304;
  ushort* fA  = hB + 4194304;
  ushort* fB  = fA + 4194304;
  ushort* At  = fB + 4194304;
  ushort* Bt  = At + 2097152;
  ushort* Wt1 = Bt + 2097152;
  ushort* Wt2 = Wt1 + 32768;     // total ~42.2 MB

  prep_transpose<<<dim3(64, 2, 8), 256, 0, stream>>>(A, Bm, At, Bt);
  prep_w<<<256, 256, 0, stream>>>(W1, W2, Wt1, Wt2);
  mlp2<128, true ><<<dim3(256, 2), 256, 0, stream>>>(A, Bm, Wt1, b1, hA, hB);
  mlp2<256, false><<<dim3(256, 2), 256, 0, stream>>>(hA, hB, Wt2, b2, fA, fB);
  flash2<<<dim3(8, 32), 256, 0, stream>>>(fA, fB, At, Bt, out);
}

// Round 3
// 237.405 us; speedup vs baseline: 2.1150x; 1.2951x over previous
//
#include <hip/hip_runtime.h>

typedef __attribute__((ext_vector_type(8))) short bf16x8;
typedef __attribute__((ext_vector_type(4))) float f32x4;
typedef __attribute__((ext_vector_type(16))) float f32x16;

__device__ __forceinline__ ushort f2bf(float x) {
  union { float f; unsigned u; } c; c.f = x;
  unsigned u = c.u;
  u += 0x7fffu + ((u >> 16) & 1u);
  return (ushort)(u >> 16);
}

__device__ __forceinline__ unsigned cvt_pk_bf16(float lo, float hi) {
  unsigned r;
  asm("v_cvt_pk_bf16_f32 %0, %1, %2" : "=v"(r) : "v"(lo), "v"(hi));
  return r;
}

__device__ __forceinline__ void gl_lds16(const void* g, void* s) {
  __builtin_amdgcn_global_load_lds(
      (const __attribute__((address_space(1))) unsigned*)g,
      (__attribute__((address_space(3))) unsigned*)s, 16, 0, 0);
}

// ---------------------------------------------------------------------------
// Transpose A,B [4][4096][128] f32 -> At,Bt [4][128][4096] bf16 (V^T operands)
// ---------------------------------------------------------------------------
__global__ __launch_bounds__(256) void prep_transpose(
    const float* __restrict__ A, const float* __restrict__ Bm,
    ushort* __restrict__ At, ushort* __restrict__ Bt)
{
  int tensor = blockIdx.z & 1, b = blockIdx.z >> 1;
  const float* in = tensor ? Bm : A;
  ushort* out = tensor ? Bt : At;
  int m0 = blockIdx.x * 64, d0 = blockIdx.y * 64;
  __shared__ ushort tile[64][72];
  int tid = threadIdx.x;
#pragma unroll
  for (int it = 0; it < 4; ++it) {
    int lin = it * 256 + tid;
    int r = lin >> 4, c4 = (lin & 15) * 4;
    const float* p = in + ((size_t)b * 4096 + m0 + r) * 128 + d0 + c4;
    float4 v = *(const float4*)p;
    tile[r][c4 + 0] = f2bf(v.x); tile[r][c4 + 1] = f2bf(v.y);
    tile[r][c4 + 2] = f2bf(v.z); tile[r][c4 + 3] = f2bf(v.w);
  }
  __syncthreads();
#pragma unroll
  for (int it = 0; it < 2; ++it) {
    int lin = it * 256 + tid;
    int dr = lin >> 3, cm = (lin & 7) * 8;
    bf16x8 v;
#pragma unroll
    for (int j = 0; j < 8; ++j) v[j] = (short)tile[cm + j][dr];
    *(bf16x8*)(out + ((size_t)b * 128 + d0 + dr) * 4096 + m0 + cm) = v;
  }
}

// ---------------------------------------------------------------------------
// W1[128][256] -> Wt1[256][128] bf16 ; W2[256][256] -> Wt2[256][256] bf16
// ---------------------------------------------------------------------------
__global__ __launch_bounds__(256) void prep_w(
    const float* __restrict__ W1, const float* __restrict__ W2,
    ushort* __restrict__ Wt1, ushort* __restrict__ Wt2)
{
  int idx = blockIdx.x * 256 + threadIdx.x;   // 0..65535
  if (idx < 32768) {
    int k = idx >> 8, n = idx & 255;
    Wt1[n * 128 + k] = f2bf(W1[idx]);
  }
  {
    int k = idx >> 8, n = idx & 255;
    Wt2[n * 256 + k] = f2bf(W2[idx]);
  }
}

// ---------------------------------------------------------------------------
// out = relu(X @ W + bias) bf16, N=256. Wt bf16 [256][KD] from global (L2).
// ---------------------------------------------------------------------------
template<int KD, bool F32IN>
__global__ __launch_bounds__(256) void mlp2(
    const void* __restrict__ X0, const void* __restrict__ X1,
    const ushort* __restrict__ Wt, const float* __restrict__ bias,
    ushort* __restrict__ out0, ushort* __restrict__ out1)
{
  const void* X = blockIdx.y ? X1 : X0;
  ushort* out = blockIdx.y ? out1 : out0;
  int l = threadIdx.x & 63, w = threadIdx.x >> 6;
  int rowbase = blockIdx.x * 64 + w * 16;
  constexpr int NK = KD / 32;
  bf16x8 xf[NK];
  {
    int r = rowbase + (l & 15);
    int koff = (l >> 4) * 8;
    if (F32IN) {
      const float* Xp = (const float*)X + (size_t)r * KD + koff;
#pragma unroll
      for (int kc = 0; kc < NK; ++kc) {
        float4 a = *(const float4*)(Xp + kc * 32);
        float4 c = *(const float4*)(Xp + kc * 32 + 4);
        bf16x8 v;
        v[0] = (short)f2bf(a.x); v[1] = (short)f2bf(a.y);
        v[2] = (short)f2bf(a.z); v[3] = (short)f2bf(a.w);
        v[4] = (short)f2bf(c.x); v[5] = (short)f2bf(c.y);
        v[6] = (short)f2bf(c.z); v[7] = (short)f2bf(c.w);
        xf[kc] = v;
      }
    } else {
      const ushort* Xp = (const ushort*)X + (size_t)r * KD + koff;
#pragma unroll
      for (int kc = 0; kc < NK; ++kc) xf[kc] = *(const bf16x8*)(Xp + kc * 32);
    }
  }
  f32x4 acc[16];
#pragma unroll
  for (int i = 0; i < 16; ++i) acc[i] = (f32x4){0.f, 0.f, 0.f, 0.f};
#pragma unroll
  for (int kc = 0; kc < NK; ++kc) {
#pragma unroll
    for (int nf = 0; nf < 16; ++nf) {
      bf16x8 bfv = *(const bf16x8*)&Wt[(size_t)(nf * 16 + (l & 15)) * KD + kc * 32 + (l >> 4) * 8];
      acc[nf] = __builtin_amdgcn_mfma_f32_16x16x32_bf16(xf[kc], bfv, acc[nf], 0, 0, 0);
    }
  }
#pragma unroll
  for (int nf = 0; nf < 16; ++nf) {
    int col = nf * 16 + (l & 15);
    float bv = bias[col];
#pragma unroll
    for (int i = 0; i < 4; ++i) {
      float v = acc[nf][i] + bv;
      v = fmaxf(v, 0.f);
      out[(size_t)(rowbase + (l >> 4) * 4 + i) * 256 + col] = f2bf(v);
    }
  }
}

// ---------------------------------------------------------------------------
// Flash pass, split-K across waves. Block = 4 waves = (qw in {0,1}) x (kw in
// {0,1}); 64 q-rows/block; wave handles 32 q-rows x 32 keys of each 64-key
// tile. Grid (8, 64) = 512 blocks -> 2 independent blocks/CU, 8 waves/CU.
// End merge of (m,l,acc) between kw partners via LDS.
// ---------------------------------------------------------------------------
__global__ __launch_bounds__(256, 2) void flash2(
    const ushort* __restrict__ fA, const ushort* __restrict__ fB,
    const ushort* __restrict__ At, const ushort* __restrict__ Bt,
    float* __restrict__ out)
{
  int bp = blockIdx.x;
  int pass = bp >> 2, b = bp & 3;
  int qbase = blockIdx.y * 64;
  const ushort* fQ = pass ? fB : fA;
  const ushort* fK = pass ? fA : fB;
  const ushort* Vg = pass ? At : Bt;
  float* O = out + (size_t)pass * (4u * 4096 * 128) + (size_t)b * 4096 * 128;

  __shared__ ushort Kl[2][64 * 256];   // 64 KB (also reused for final merge)

  int tid = threadIdx.x;
  int l = tid & 63, w = tid >> 6;
  int l31 = l & 31, g5 = l >> 5;
  int qw = w & 1, kw = w >> 1;

  const size_t fkbase = (size_t)b * 4096 * 256;
  const size_t vgbase = (size_t)b * 128 * 4096;

  auto stage_k = [&](int t_, int buf_) {
    const ushort* kp = fK + fkbase + (size_t)t_ * 16384;
    ushort* lb = &Kl[buf_][0] + w * 4096;
#pragma unroll
    for (int s = 0; s < 8; ++s) {
      int row = w * 16 + s * 2 + g5;
      int gs = l31 ^ (row & 7);
      gl_lds16(kp + (size_t)row * 256 + gs * 8, lb + s * 512);
    }
  };

  // Q regs: B-frag (col = l31 -> qrow, k = kc*16 + g5*8 + j)
  bf16x8 q[16];
  {
    const ushort* qp = fQ + fkbase + (size_t)(qbase + qw * 32 + l31) * 256 + g5 * 8;
#pragma unroll
    for (int kc = 0; kc < 16; ++kc) q[kc] = *(const bf16x8*)(qp + kc * 16);
  }

  f32x16 acc_o0 = {}, acc_o1 = {}, acc_o2 = {}, acc_o3 = {};
  float m_run = -INFINITY, l_run = 0.f;

  stage_k(0, 0);

  for (int t = 0; t < 64; ++t) {
    int cur = t & 1;
    __syncthreads();               // staged K[t] drained; prev reads done
    if (t < 63) stage_k(t + 1, cur ^ 1);

    // V^T loads (L2): B-frag col = l31 -> d-local, k = key-local
    bf16x8 vv[2][4];
#pragma unroll
    for (int dblk = 0; dblk < 4; ++dblk) {
      const ushort* vp = Vg + vgbase + (size_t)(dblk * 32 + l31) * 4096
                         + t * 64 + kw * 32 + g5 * 8;
#pragma unroll
      for (int kblk = 0; kblk < 2; ++kblk)
        vv[kblk][dblk] = *(const bf16x8*)(vp + kblk * 16);
    }

    // QK^T swapped: S^T[key][qrow] = mfma(A=K, B=Q). 2 indep chains.
    const ushort* kbuf = &Kl[cur][0];
    int krow = kw * 32 + l31;
    int sx = l31 & 7;
    f32x16 s0 = {}, s1 = {};
#pragma unroll
    for (int kc = 0; kc < 8; ++kc) {
      bf16x8 a0 = *(const bf16x8*)&kbuf[krow * 256 + (((4 * kc + g5) ^ sx) * 8)];
      bf16x8 a1 = *(const bf16x8*)&kbuf[krow * 256 + (((4 * kc + 2 + g5) ^ sx) * 8)];
      s0 = __builtin_amdgcn_mfma_f32_32x32x16_bf16(a0, q[2 * kc],     s0, 0, 0, 0);
      s1 = __builtin_amdgcn_mfma_f32_32x32x16_bf16(a1, q[2 * kc + 1], s1, 0, 0, 0);
    }

    // lane: qrow = l31; key-local(r,g5) = (r&3) + 8*(r>>2) + 4*g5  in [0,32)
    float sv[16];
#pragma unroll
    for (int r = 0; r < 16; ++r) sv[r] = s0[r] + s1[r];

    float pmax = sv[0];
#pragma unroll
    for (int r = 1; r < 16; ++r) pmax = fmaxf(pmax, sv[r]);
    pmax = fmaxf(pmax, __shfl_xor(pmax, 32));

    if (!__all(pmax <= m_run + 8.f)) {       // rare (t=0 / overflow risk only)
      float mnew = fmaxf(m_run, pmax);
      float sc = __expf(m_run - mnew);
      l_run *= sc;
#pragma unroll
      for (int r = 0; r < 16; ++r) {
        float scr = __shfl(sc, (r & 3) + 8 * (r >> 2) + 4 * g5);
        acc_o0[r] *= scr; acc_o1[r] *= scr; acc_o2[r] *= scr; acc_o3[r] *= scr;
      }
      m_run = mnew;
    }

    float p[16], psum = 0.f;
#pragma unroll
    for (int r = 0; r < 16; ++r) {
      p[r] = __expf(sv[r] - m_run);
      psum += p[r];
    }
    l_run += psum + __shfl_xor(psum, 32);

    // pack P pairs: pk[r2][h] covers key-locals 4*(2*r2 + g5) + {0..3}
    unsigned pk[4][2];
#pragma unroll
    for (int r2 = 0; r2 < 4; ++r2) {
      pk[r2][0] = cvt_pk_bf16(p[4 * r2 + 0], p[4 * r2 + 1]);
      pk[r2][1] = cvt_pk_bf16(p[4 * r2 + 2], p[4 * r2 + 3]);
    }

    // exchange halves -> PV A-frags; PV MFMAs
#pragma unroll
    for (int kblk = 0; kblk < 2; ++kblk) {
      int r2a = 2 * kblk, r2b = r2a + 1;
      unsigned la0 = pk[r2a][0], la1 = pk[r2a][1];
      unsigned lb0 = pk[r2b][0], lb1 = pk[r2b][1];
      unsigned s0w = g5 ? la0 : lb0, s1w = g5 ? la1 : lb1;
      unsigned rc0 = (unsigned)__shfl_xor((int)s0w, 32);
      unsigned rc1 = (unsigned)__shfl_xor((int)s1w, 32);
      union { unsigned u[4]; bf16x8 v; } pf;
      pf.u[0] = g5 ? rc0 : la0;  pf.u[1] = g5 ? rc1 : la1;
      pf.u[2] = g5 ? lb0 : rc0;  pf.u[3] = g5 ? lb1 : rc1;
      acc_o0 = __builtin_amdgcn_mfma_f32_32x32x16_bf16(pf.v, vv[kblk][0], acc_o0, 0, 0, 0);
      acc_o1 = __builtin_amdgcn_mfma_f32_32x32x16_bf16(pf.v, vv[kblk][1], acc_o1, 0, 0, 0);
      acc_o2 = __builtin_amdgcn_mfma_f32_32x32x16_bf16(pf.v, vv[kblk][2], acc_o2, 0, 0, 0);
      acc_o3 = __builtin_amdgcn_mfma_f32_32x32x16_bf16(pf.v, vv[kblk][3], acc_o3, 0, 0, 0);
    }
  }

  // ---- merge kw partners through LDS, then store ----
  __syncthreads();                 // all K reads done; Kl reusable
  float* shm = (float*)&Kl[0][0];
  // layout: [w*128 + l] = m ; [w*128 + 64 + l] = l_run ; acc at 512 + w*2048
  shm[w * 128 + l] = m_run;
  shm[w * 128 + 64 + l] = l_run;
  {
    float* sa = shm + 512 + w * 2048;
    const f32x16& send0 = kw ? acc_o0 : acc_o2;
    const f32x16& send1 = kw ? acc_o1 : acc_o3;
#pragma unroll
    for (int r = 0; r < 16; ++r) {
      sa[r * 64 + l] = send0[r];
      sa[1024 + r * 64 + l] = send1[r];
    }
  }
  __syncthreads();
  {
    int pw = w ^ 2;
    float m1 = shm[pw * 128 + l];
    float l1 = shm[pw * 128 + 64 + l];
    float M = fmaxf(m_run, m1);
    float a0 = __expf(m_run - M), a1 = __expf(m1 - M);
    float inv = 1.f / (l_run * a0 + l1 * a1);
    const float* sp = shm + 512 + pw * 2048;
    const f32x16& keep0 = kw ? acc_o2 : acc_o0;
    const f32x16& keep1 = kw ? acc_o3 : acc_o1;
    int dbase = kw ? 64 : 0;
    int qr = qbase + qw * 32;
#pragma unroll
    for (int r = 0; r < 16; ++r) {
      int rowl = (r & 3) + 8 * (r >> 2) + 4 * g5;
      float invr = __shfl(inv, rowl);
      float a0r = __shfl(a0, rowl);
      float a1r = __shfl(a1, rowl);
      float* op = O + (size_t)(qr + rowl) * 128 + dbase + l31;
      op[0]  = (keep0[r] * a0r + sp[r * 64 + l] * a1r) * invr;
      op[32] = (keep1[r] * a0r + sp[1024 + r * 64 + l] * a1r) * invr;
    }
  }
}

// ---------------------------------------------------------------------------
extern "C" void kernel_launch(void* const* d_in, const int* in_sizes, int n_in,
                              void* d_out, int out_size, void* d_ws, size_t ws_size,
                              hipStream_t stream) {
  const float* A  = (const float*)d_in[0];
  const float* Bm = (const float*)d_in[1];
  const float* W1 = (const float*)d_in[2];
  const float* b1 = (const float*)d_in[3];
  const float* W2 = (const float*)d_in[4];
  const float* b2 = (const float*)d_in[5];
  float* out = (float*)d_out;

  // ws (ushort units): hA,hB,fA,fB [16384][256]; At,Bt [4][128][4096]; Wt1,Wt2
  ushort* ws = (ushort*)d_ws;
  ushort* hA  = ws;
  ushort* hB  = hA + 4194304;
  ushort* fA  = hB + 4194304;
  ushort* fB  = fA + 4194304;
  ushort* At  = fB + 4194304;
  ushort* Bt  = At + 2097152;
  ushort* Wt1 = Bt + 2097152;
  ushort* Wt2 = Wt1 + 32768;     // total ~42.2 MB

  prep_transpose<<<dim3(64, 2, 8), 256, 0, stream>>>(A, Bm, At, Bt);
  prep_w<<<256, 256, 0, stream>>>(W1, W2, Wt1, Wt2);
  mlp2<128, true ><<<dim3(256, 2), 256, 0, stream>>>(A, Bm, Wt1, b1, hA, hB);
  mlp2<256, false><<<dim3(256, 2), 256, 0, stream>>>(hA, hB, Wt2, b2, fA, fB);
  flash2<<<dim3(8, 64), 256, 0, stream>>>(fA, fB, At, Bt, out);
}